// Round 6
// baseline (522.107 us; speedup 1.0000x reference)
//
#include <hip/hip_runtime.h>
#include <math.h>

// Problem constants (static shapes from setup_inputs; all arrays are float32)
#define B_   2
#define T_   8
#define R_   128
#define NP_  32768
#define F_   5
#define S_   32           // num_sample
#define SEG_ 2048         // points per phase-1 segment
#define NSEG (NP_ / SEG_) // 16
#define NBT  (B_ * T_)    // 16
#define NROW (NBT * R_)   // 2048
#define RPB  8            // rois per block (2 per wave)
#define NGRP (NBT * (R_ / RPB))  // 256 gather groups (bt, rg)

__device__ __forceinline__ int mbcnt64(unsigned long long m) {
    return __builtin_amdgcn_mbcnt_hi((unsigned)(m >> 32),
           __builtin_amdgcn_mbcnt_lo((unsigned)m, 0u));
}

// ---------- kernel 1: vectorized AoS->SoA xy transpose + per-row constants + zero arrivals ----------
// T = max{ x : sqrtf(x) <= radius } makes the phase-1 predicate sqrt-free yet
// bit-identical (sqrtf monotone + correctly rounded).
__global__ __launch_bounds__(256) void xy_transpose_prep(
    const float* __restrict__ points,  // [bt, Np, 5]
    const float* __restrict__ rois,    // [bt, R, 9]
    float2* __restrict__ xy,           // [bt, Np]
    float4* __restrict__ rowc,         // [row] = {cx, cy, T, 0}
    unsigned int* __restrict__ done)   // [NGRP] arrival counters
{
    const int j = blockIdx.x * blockDim.x + threadIdx.x;
    if (j < NBT * NP_ / 4) {
        const float4* src = (const float4*)points + (size_t)j * 5;
        const float4 a = src[0], b = src[1], c = src[2], d = src[3], e = src[4];
        float4* dst = (float4*)xy + (size_t)j * 2;
        dst[0] = make_float4(a.x, a.y, b.y, b.z);   // pts 4j, 4j+1
        dst[1] = make_float4(c.z, c.w, d.w, e.x);   // pts 4j+2, 4j+3
    }
    if (j < NGRP) done[j] = 0u;
    if (j < NROW) {
        const int row = j;                 // row = bt*R + r
        const int bt  = row / R_;
        const int t   = bt % T_;
        const float* roi = rois + (size_t)row * 9;
        const float cx = roi[0], cy = roi[1];
        const float hx = roi[3] * 0.5f, hy = roi[4] * 0.5f;
        const float vx = roi[7], vy = roi[8];
        const float speed  = sqrtf(vx * vx + vy * vy);
        const float base_g = 1.05f * (1.0f + speed);
        const float expo   = (float)t / 5.0f;
        const float gamma  = fminf((float)pow((double)base_g, (double)expo), 2.5f);
        const float radius = sqrtf(hx * hx + hy * hy) * gamma;
        // ulp-walk: largest float T with sqrtf(T) <= radius
        unsigned ut = __float_as_uint(radius * radius);
        while (sqrtf(__uint_as_float(ut)) > radius) --ut;
        while (sqrtf(__uint_as_float(ut + 1u)) <= radius) ++ut;
        rowc[row] = make_float4(cx, cy, __uint_as_float(ut), 0.0f);
    }
}

// ---------- kernel 2: LDS-staged ordered hit collection + fused last-block gather ----------
// block = 256 (4 waves) on one (bt, seg): stage 16 KB xy segment to LDS once,
// each wave scans it for 2 rois (2 points/lane/ds_read_b128). The 16th block
// of each (bt, rg) group to finish gathers its 8 rows' output (phase-2 work).
__global__ __launch_bounds__(256) void phase1_collect_gather(
    const float2* __restrict__ xy,        // [bt, Np]
    const float4* __restrict__ rowc,      // [row]
    const float* __restrict__ points,     // [bt, Np, 5]
    int* __restrict__ counts,             // [row, NSEG]
    unsigned short* __restrict__ hitidx,  // [row, NSEG, S_]
    unsigned int* __restrict__ done,      // [NGRP]
    float* __restrict__ out)              // [B, R, T*S, 5]
{
    __shared__ float4 tile[SEG_ / 2];     // 16 KB: 1024 point-pairs
    __shared__ int is_last;

    const int blk = blockIdx.x;                 // (bt*NSEG + seg)*(R_/RPB) + rg
    const int rg  = blk % (R_ / RPB);
    const int bs  = blk / (R_ / RPB);
    const int seg = bs % NSEG;
    const int bt  = bs / NSEG;
    const int w    = threadIdx.x >> 6;
    const int lane = threadIdx.x & 63;

    // cooperative stage: 1024 float4 / 256 threads = 4 each (coalesced)
    const float4* src = (const float4*)(xy + (size_t)bt * NP_ + (size_t)seg * SEG_);
    #pragma unroll
    for (int i = 0; i < 4; ++i)
        tile[i * 256 + threadIdx.x] = src[i * 256 + threadIdx.x];
    __syncthreads();

    const int row0 = bt * R_ + rg * RPB + w * 2;
    const int row1 = row0 + 1;
    const float4 rc0 = rowc[row0], rc1 = rowc[row1];
    unsigned short* h0 = hitidx + ((size_t)row0 * NSEG + seg) * S_;
    unsigned short* h1 = hitidx + ((size_t)row1 * NSEG + seg) * S_;

    int sel0 = 0, sel1 = 0;
    const int ibase = seg * SEG_;
    #pragma unroll 2
    for (int it = 0; it < SEG_ / 128; ++it) {   // 16 iterations
        const float4 q = tile[it * 64 + lane];  // points idx0, idx0+1
        const int idx0 = ibase + (it * 64 + lane) * 2;

        // strict numpy rounding: mul, mul, add separately rounded (no fma)
        {
            const float ax = __fsub_rn(q.x, rc0.x), ay = __fsub_rn(q.y, rc0.y);
            const float bx = __fsub_rn(q.z, rc0.x), by = __fsub_rn(q.w, rc0.y);
            const float d2a = __fadd_rn(__fmul_rn(ax, ax), __fmul_rn(ay, ay));
            const float d2b = __fadd_rn(__fmul_rn(bx, bx), __fmul_rn(by, by));
            const bool p0 = (d2a <= rc0.z), p1 = (d2b <= rc0.z);
            const unsigned long long m0 = __ballot(p0), m1 = __ballot(p1);
            if (m0 | m1) {
                const int base = sel0 + mbcnt64(m0) + mbcnt64(m1);
                if (p0 && base < S_) h0[base] = (unsigned short)idx0;
                if (p1) { const int s = base + (p0 ? 1 : 0);
                          if (s < S_) h0[s] = (unsigned short)(idx0 + 1); }
                sel0 += __popcll(m0) + __popcll(m1);
            }
        }
        {
            const float ax = __fsub_rn(q.x, rc1.x), ay = __fsub_rn(q.y, rc1.y);
            const float bx = __fsub_rn(q.z, rc1.x), by = __fsub_rn(q.w, rc1.y);
            const float d2a = __fadd_rn(__fmul_rn(ax, ax), __fmul_rn(ay, ay));
            const float d2b = __fadd_rn(__fmul_rn(bx, bx), __fmul_rn(by, by));
            const bool p0 = (d2a <= rc1.z), p1 = (d2b <= rc1.z);
            const unsigned long long m0 = __ballot(p0), m1 = __ballot(p1);
            if (m0 | m1) {
                const int base = sel1 + mbcnt64(m0) + mbcnt64(m1);
                if (p0 && base < S_) h1[base] = (unsigned short)idx0;
                if (p1) { const int s = base + (p0 ? 1 : 0);
                          if (s < S_) h1[s] = (unsigned short)(idx0 + 1); }
                sel1 += __popcll(m0) + __popcll(m1);
            }
        }
    }
    if (lane == 0) {
        counts[(size_t)row0 * NSEG + seg] = (sel0 < S_) ? sel0 : S_;
        counts[(size_t)row1 * NSEG + seg] = (sel1 < S_) ? sel1 : S_;
    }

    // ---- release: my stores -> agent scope, then arrive ----
    __threadfence();                 // every thread releases its own stores
    __syncthreads();                 // all releases happen-before the arrive
    if (threadIdx.x == 0) {
        const unsigned int g = (unsigned int)(bt * (R_ / RPB) + rg);
        is_last = (atomicAdd(&done[g], 1u) == NSEG - 1u) ? 1 : 0;
    }
    __syncthreads();
    if (!is_last) return;

    // ---- acquire + gather (phase-2): 8 rows x 32 slots = 256 threads ----
    __threadfence();
    const int slot = threadIdx.x & (S_ - 1);
    const int row  = bt * R_ + rg * RPB + (threadIdx.x >> 5);
    const int r = row % R_;
    const int t = bt % T_;
    const int b = bt / T_;

    const int4* cp = (const int4*)(counts + (size_t)row * NSEG);
    const int4 q0 = cp[0], q1 = cp[1], q2 = cp[2], q3 = cp[3];
    const int cs[16] = {q0.x,q0.y,q0.z,q0.w, q1.x,q1.y,q1.z,q1.w,
                        q2.x,q2.y,q2.z,q2.w, q3.x,q3.y,q3.z,q3.w};
    int sg = -1, local = 0, acc = 0;
    #pragma unroll
    for (int s = 0; s < NSEG; ++s) {
        const int na = acc + cs[s];
        if (sg < 0 && slot < na) { sg = s; local = slot - acc; }
        acc = na;
    }
    const int total = (acc < S_) ? acc : S_;

    float* o = out + (((((size_t)b * R_ + r) * T_ + t) * S_) + slot) * F_;
    if (slot < total) {
        const int pi = hitidx[((size_t)row * NSEG + sg) * S_ + local];
        const float* p = points + ((size_t)bt * NP_ + pi) * F_;
        o[0] = p[0]; o[1] = p[1]; o[2] = p[2]; o[3] = p[3]; o[4] = p[4];
    } else {
        o[0] = 0.0f; o[1] = 0.0f; o[2] = 0.0f; o[3] = 0.0f; o[4] = 0.0f;
    }
}

extern "C" void kernel_launch(void* const* d_in, const int* in_sizes, int n_in,
                              void* d_out, int out_size, void* d_ws, size_t ws_size,
                              hipStream_t stream) {
    const float* points = (const float*)d_in[0];
    const float* rois   = (const float*)d_in[1];
    float* out = (float*)d_out;

    // workspace layout (~6.5 MB)
    char* ws = (char*)d_ws;
    float2* xy             = (float2*)ws;                                   // 4,194,304 B
    int* counts            = (int*)(ws + 4194304);                          //   131,072 B
    unsigned short* hitidx = (unsigned short*)(ws + 4194304 + 131072);      // 2,097,152 B
    float4* rowc           = (float4*)(ws + 4194304 + 131072 + 2097152);    //    32,768 B
    unsigned int* done     = (unsigned int*)(ws + 4194304 + 131072 + 2097152 + 32768); // 1,024 B

    // 1) vectorized transpose + per-row constants + zero arrival counters
    xy_transpose_prep<<<(NBT * NP_ / 4 + 255) / 256, 256, 0, stream>>>(points, rois, xy, rowc, done);

    // 2) fused collect + last-block gather: 16 bt x 16 seg x 16 roi-groups
    phase1_collect_gather<<<NBT * NSEG * (R_ / RPB), 256, 0, stream>>>(
        xy, rowc, points, counts, hitidx, done, out);
}

// Round 7
// 91.541 us; speedup vs baseline: 5.7035x; 5.7035x over previous
//
#include <hip/hip_runtime.h>
#include <math.h>

// Problem constants (static shapes from setup_inputs; all arrays are float32)
#define B_   2
#define T_   8
#define R_   128
#define NP_  32768
#define F_   5
#define S_   32           // num_sample
#define SEG_ 2048         // points per LDS-staged segment
#define NSEG (NP_ / SEG_) // 16
#define NBT  (B_ * T_)    // 16
#define RPB  8            // rois per block (1 per wave)
#define NGRP (NBT * (R_ / RPB))  // 256 blocks = 1 per CU

__device__ __forceinline__ int mbcnt64(unsigned long long m) {
    return __builtin_amdgcn_mbcnt_hi((unsigned)(m >> 32),
           __builtin_amdgcn_mbcnt_lo((unsigned)m, 0u));
}

// Single fused kernel. Block = (bt, rg): 8 waves, wave w scans roi rg*8+w over
// all 16 segments (ascending), double-buffered LDS xy tile, hits collected in
// LDS; final 256 threads gather output. No workspace, no cross-block sync.
__global__ __launch_bounds__(512) void voxel_sampler_fused(
    const float* __restrict__ points,  // [bt, Np, 5]
    const float* __restrict__ rois,    // [bt, R, 9]
    float* __restrict__ out)           // [B, R, T*S, 5]
{
    __shared__ float4 tile[2][SEG_ / 2];        // 2 x 16 KB point-pair buffers
    __shared__ unsigned short hits_l[RPB][S_];  // first 32 hit indices per roi
    __shared__ int cnt_l[RPB];

    const int blk  = blockIdx.x;        // bt * (R_/RPB) + rg
    const int rg   = blk % (R_ / RPB);
    const int bt   = blk / (R_ / RPB);
    const int tid  = threadIdx.x;
    const int w    = tid >> 6;          // wave 0..7
    const int lane = tid & 63;

    // ---- per-wave roi constants (all lanes redundantly; f32 op-for-op vs numpy) ----
    const int r = rg * RPB + w;
    const int t = bt % T_;
    const int b = bt / T_;
    const float* roi = rois + ((size_t)bt * R_ + r) * 9;
    const float cx = roi[0], cy = roi[1];
    const float hx = roi[3] * 0.5f, hy = roi[4] * 0.5f;
    const float vx = roi[7], vy = roi[8];
    const float speed  = sqrtf(vx * vx + vy * vy);
    const float base_g = 1.05f * (1.0f + speed);
    const float expo   = (float)t / 5.0f;
    const float gamma  = fminf((float)pow((double)base_g, (double)expo), 2.5f);
    const float radius = sqrtf(hx * hx + hy * hy) * gamma;
    // T = max{ x : sqrtf(x) <= radius }  (sqrt-free predicate, bit-identical)
    unsigned ut = __float_as_uint(radius * radius);
    while (sqrtf(__uint_as_float(ut)) > radius) --ut;
    while (sqrtf(__uint_as_float(ut + 1u)) <= radius) ++ut;
    const float Tthr = __uint_as_float(ut);

    // ---- stage segment 0: thread stages points 4*tid..4*tid+3 (5 float4 -> 2 float4) ----
    const float4* src = (const float4*)(points + (size_t)bt * NP_ * F_);
    {
        const float4* s0 = src + (size_t)tid * 5;
        const float4 a = s0[0], bq = s0[1], c = s0[2], d = s0[3], e = s0[4];
        tile[0][tid * 2]     = make_float4(a.x, a.y, bq.y, bq.z);  // pts 4t, 4t+1
        tile[0][tid * 2 + 1] = make_float4(c.z, c.w, d.w, e.x);    // pts 4t+2, 4t+3
    }
    __syncthreads();

    int sel = 0;
    for (int s = 0; s < NSEG; ++s) {
        // prefetch next segment's AoS into registers (latency overlapped with scan)
        float4 pa, pb, pc, pd, pe;
        const bool more = (s + 1 < NSEG);
        if (more) {
            const float4* sn = src + (size_t)(s + 1) * (SEG_ * F_ / 4) + (size_t)tid * 5;
            pa = sn[0]; pb = sn[1]; pc = sn[2]; pd = sn[3]; pe = sn[4];
        }
        // scan current buffer (skip if this roi already has 32 hits; wave-uniform)
        if (sel < S_) {
            const int buf = s & 1;
            const int ibase = s * SEG_;
            #pragma unroll 4
            for (int it = 0; it < SEG_ / 128; ++it) {   // 16 iters, 2 pts/lane
                const float4 q = tile[buf][it * 64 + lane];
                const int idx0 = ibase + (it * 64 + lane) * 2;
                // strict numpy rounding: sub, mul, mul, add separately rounded
                const float ax = __fsub_rn(q.x, cx), ay = __fsub_rn(q.y, cy);
                const float bx = __fsub_rn(q.z, cx), by = __fsub_rn(q.w, cy);
                const float d2a = __fadd_rn(__fmul_rn(ax, ax), __fmul_rn(ay, ay));
                const float d2b = __fadd_rn(__fmul_rn(bx, bx), __fmul_rn(by, by));
                const bool p0 = (d2a <= Tthr), p1 = (d2b <= Tthr);
                const unsigned long long m0 = __ballot(p0), m1 = __ballot(p1);
                if (m0 | m1) {
                    const int base = sel + mbcnt64(m0) + mbcnt64(m1);
                    if (p0 && base < S_) hits_l[w][base] = (unsigned short)idx0;
                    if (p1) { const int sl = base + (p0 ? 1 : 0);
                              if (sl < S_) hits_l[w][sl] = (unsigned short)(idx0 + 1); }
                    sel += __popcll(m0) + __popcll(m1);
                }
            }
        }
        // write prefetched data into the other buffer (safe: that buffer's last
        // readers finished at the previous barrier), then one barrier per segment
        if (more) {
            tile[(s + 1) & 1][tid * 2]     = make_float4(pa.x, pa.y, pb.y, pb.z);
            tile[(s + 1) & 1][tid * 2 + 1] = make_float4(pc.z, pc.w, pd.w, pe.x);
        }
        __syncthreads();
    }
    if (lane == 0) cnt_l[w] = (sel < S_) ? sel : S_;
    __syncthreads();

    // ---- gather: threads 0..255 -> (roi_local, slot) ----
    if (tid < RPB * S_) {
        const int rl   = tid >> 5;
        const int slot = tid & (S_ - 1);
        const int rr   = rg * RPB + rl;
        float* o = out + ((((size_t)b * R_ + rr) * T_ + t) * S_ + slot) * F_;
        if (slot < cnt_l[rl]) {
            const int pi = hits_l[rl][slot];
            const float* p = points + ((size_t)bt * NP_ + pi) * F_;
            o[0] = p[0]; o[1] = p[1]; o[2] = p[2]; o[3] = p[3]; o[4] = p[4];
        } else {
            o[0] = 0.0f; o[1] = 0.0f; o[2] = 0.0f; o[3] = 0.0f; o[4] = 0.0f;
        }
    }
}

extern "C" void kernel_launch(void* const* d_in, const int* in_sizes, int n_in,
                              void* d_out, int out_size, void* d_ws, size_t ws_size,
                              hipStream_t stream) {
    const float* points = (const float*)d_in[0];
    const float* rois   = (const float*)d_in[1];
    float* out = (float*)d_out;
    // d_in[2] = num_sample (==32) baked into S_; d_ws unused.
    voxel_sampler_fused<<<NGRP, 512, 0, stream>>>(points, rois, out);
}

// Round 8
// 88.378 us; speedup vs baseline: 5.9077x; 1.0358x over previous
//
#include <hip/hip_runtime.h>
#include <math.h>

// Problem constants (static shapes from setup_inputs; all arrays are float32)
#define B_   2
#define T_   8
#define R_   128
#define NP_  32768
#define F_   5
#define S_   32           // num_sample
#define SEG_ 2048         // points per phase-1 segment
#define NSEG (NP_ / SEG_) // 16
#define NBT  (B_ * T_)    // 16
#define NROW (NBT * R_)   // 2048
#define RPB  8            // rois per block (2 per wave, 4 waves)

__device__ __forceinline__ int mbcnt64(unsigned long long m) {
    return __builtin_amdgcn_mbcnt_hi((unsigned)(m >> 32),
           __builtin_amdgcn_mbcnt_lo((unsigned)m, 0u));
}

// ---------- kernel 1: AoS-staged segmented ordered hit collection ----------
// block = 256 (4 waves) on one (bt, seg): stage the 40 KB AoS slab as a packed
// 16 KB xy tile in LDS (repack in registers), then each wave scans it for 2
// rois (2 points/lane/ds_read_b128). Per-row constants (pow + ulp-walk for the
// sqrt-free threshold T = max{x : sqrtf(x) <= radius}, bit-identical selection)
// are computed inline by lanes 0-1 of each wave and broadcast via shuffle.
__global__ __launch_bounds__(256) void phase1_collect(
    const float* __restrict__ points,    // [bt, Np, 5]
    const float* __restrict__ rois,      // [bt, R, 9]
    int* __restrict__ counts,            // [row, NSEG]   (row = bt*R + r)
    unsigned short* __restrict__ hitidx) // [row, NSEG, S_]
{
    __shared__ float4 tile[SEG_ / 2];    // 16 KB: 1024 point-pairs

    const int blk = blockIdx.x;                 // (bt*NSEG + seg)*(R_/RPB) + rg
    const int rg  = blk % (R_ / RPB);
    const int bs  = blk / (R_ / RPB);
    const int seg = bs % NSEG;
    const int bt  = bs / NSEG;
    const int tid  = threadIdx.x;
    const int w    = tid >> 6;
    const int lane = tid & 63;

    // ---- stage AoS -> packed xy LDS tile: 512 groups of 4 pts (5 float4 each) ----
    const float4* src = (const float4*)(points + (size_t)bt * NP_ * F_)
                        + (size_t)seg * (SEG_ * F_ / 4);
    #pragma unroll
    for (int i = 0; i < 2; ++i) {
        const int g = tid + i * 256;            // group of 4 points
        const float4* s5 = src + (size_t)g * 5;
        const float4 a = s5[0], bq = s5[1], c = s5[2], d = s5[3], e = s5[4];
        tile[g * 2]     = make_float4(a.x, a.y, bq.y, bq.z);   // pts 4g, 4g+1
        tile[g * 2 + 1] = make_float4(c.z, c.w, d.w, e.x);     // pts 4g+2, 4g+3
    }

    // ---- per-wave roi constants: lane k (k<2) computes row0+k, then broadcast ----
    const int row0 = bt * R_ + rg * RPB + w * 2;
    float vcx = 0.0f, vcy = 0.0f, vT = 0.0f;
    if (lane < 2) {
        const int row = row0 + lane;
        const int t   = bt % T_;
        const float* roi = rois + (size_t)row * 9;
        const float cx = roi[0], cy = roi[1];
        const float hx = roi[3] * 0.5f, hy = roi[4] * 0.5f;
        const float vx = roi[7], vy = roi[8];
        const float speed  = sqrtf(vx * vx + vy * vy);
        const float base_g = 1.05f * (1.0f + speed);
        const float expo   = (float)t / 5.0f;
        const float gamma  = fminf((float)pow((double)base_g, (double)expo), 2.5f);
        const float radius = sqrtf(hx * hx + hy * hy) * gamma;
        // ulp-walk: largest float T with sqrtf(T) <= radius
        unsigned ut = __float_as_uint(radius * radius);
        while (sqrtf(__uint_as_float(ut)) > radius) --ut;
        while (sqrtf(__uint_as_float(ut + 1u)) <= radius) ++ut;
        vcx = cx; vcy = cy; vT = __uint_as_float(ut);
    }
    const float cx0 = __shfl(vcx, 0), cy0 = __shfl(vcy, 0), T0 = __shfl(vT, 0);
    const float cx1 = __shfl(vcx, 1), cy1 = __shfl(vcy, 1), T1 = __shfl(vT, 1);

    __syncthreads();

    const int row1 = row0 + 1;
    unsigned short* h0 = hitidx + ((size_t)row0 * NSEG + seg) * S_;
    unsigned short* h1 = hitidx + ((size_t)row1 * NSEG + seg) * S_;

    int sel0 = 0, sel1 = 0;
    const int ibase = seg * SEG_;
    #pragma unroll 2
    for (int it = 0; it < SEG_ / 128; ++it) {   // 16 iterations, 2 pts/lane
        const float4 q = tile[it * 64 + lane];  // points idx0, idx0+1
        const int idx0 = ibase + (it * 64 + lane) * 2;

        // strict numpy rounding: sub, mul, mul, add separately rounded (no fma)
        {
            const float ax = __fsub_rn(q.x, cx0), ay = __fsub_rn(q.y, cy0);
            const float bx = __fsub_rn(q.z, cx0), by = __fsub_rn(q.w, cy0);
            const float d2a = __fadd_rn(__fmul_rn(ax, ax), __fmul_rn(ay, ay));
            const float d2b = __fadd_rn(__fmul_rn(bx, bx), __fmul_rn(by, by));
            const bool p0 = (d2a <= T0), p1 = (d2b <= T0);
            const unsigned long long m0 = __ballot(p0), m1 = __ballot(p1);
            if (m0 | m1) {
                const int base = sel0 + mbcnt64(m0) + mbcnt64(m1);
                if (p0 && base < S_) h0[base] = (unsigned short)idx0;
                if (p1) { const int s = base + (p0 ? 1 : 0);
                          if (s < S_) h0[s] = (unsigned short)(idx0 + 1); }
                sel0 += __popcll(m0) + __popcll(m1);
            }
        }
        {
            const float ax = __fsub_rn(q.x, cx1), ay = __fsub_rn(q.y, cy1);
            const float bx = __fsub_rn(q.z, cx1), by = __fsub_rn(q.w, cy1);
            const float d2a = __fadd_rn(__fmul_rn(ax, ax), __fmul_rn(ay, ay));
            const float d2b = __fadd_rn(__fmul_rn(bx, bx), __fmul_rn(by, by));
            const bool p0 = (d2a <= T1), p1 = (d2b <= T1);
            const unsigned long long m0 = __ballot(p0), m1 = __ballot(p1);
            if (m0 | m1) {
                const int base = sel1 + mbcnt64(m0) + mbcnt64(m1);
                if (p0 && base < S_) h1[base] = (unsigned short)idx0;
                if (p1) { const int s = base + (p0 ? 1 : 0);
                          if (s < S_) h1[s] = (unsigned short)(idx0 + 1); }
                sel1 += __popcll(m0) + __popcll(m1);
            }
        }
    }
    if (lane == 0) {
        counts[(size_t)row0 * NSEG + seg] = (sel0 < S_) ? sel0 : S_;
        counts[(size_t)row1 * NSEG + seg] = (sel1 < S_) ? sel1 : S_;
    }
}

// ---------- kernel 2: prefix + gather + zero-fill ----------
// one thread per (row, slot): 65536 threads.
__global__ __launch_bounds__(256) void phase2_gather(
    const float* __restrict__ points,          // [bt, Np, 5]
    const int* __restrict__ counts,            // [row, NSEG]
    const unsigned short* __restrict__ hitidx, // [row, NSEG, S_]
    float* __restrict__ out)                   // [B, R, T*S, 5]
{
    const int tid  = blockIdx.x * blockDim.x + threadIdx.x;
    const int slot = tid & (S_ - 1);
    const int row  = tid >> 5;                 // S_ == 32
    if (row >= NROW) return;
    const int r  = row % R_;
    const int bt = row / R_;
    const int t  = bt % T_;
    const int b  = bt / T_;

    const int4* cp = (const int4*)(counts + (size_t)row * NSEG);
    const int4 q0 = cp[0], q1 = cp[1], q2 = cp[2], q3 = cp[3];
    const int cs[16] = {q0.x,q0.y,q0.z,q0.w, q1.x,q1.y,q1.z,q1.w,
                        q2.x,q2.y,q2.z,q2.w, q3.x,q3.y,q3.z,q3.w};
    int seg = -1, local = 0, acc = 0;
    #pragma unroll
    for (int s = 0; s < NSEG; ++s) {
        const int na = acc + cs[s];
        if (seg < 0 && slot < na) { seg = s; local = slot - acc; }
        acc = na;
    }
    const int total = (acc < S_) ? acc : S_;

    float* o = out + (((((size_t)b * R_ + r) * T_ + t) * S_) + slot) * F_;
    if (slot < total) {
        const int pi = hitidx[((size_t)row * NSEG + seg) * S_ + local];
        const float* p = points + ((size_t)bt * NP_ + pi) * F_;
        o[0] = p[0]; o[1] = p[1]; o[2] = p[2]; o[3] = p[3]; o[4] = p[4];
    } else {
        o[0] = 0.0f; o[1] = 0.0f; o[2] = 0.0f; o[3] = 0.0f; o[4] = 0.0f;
    }
}

extern "C" void kernel_launch(void* const* d_in, const int* in_sizes, int n_in,
                              void* d_out, int out_size, void* d_ws, size_t ws_size,
                              hipStream_t stream) {
    const float* points = (const float*)d_in[0];
    const float* rois   = (const float*)d_in[1];
    float* out = (float*)d_out;

    // workspace layout (~2.2 MB)
    char* ws = (char*)d_ws;
    int* counts            = (int*)ws;                       //   131,072 B
    unsigned short* hitidx = (unsigned short*)(ws + 131072); // 2,097,152 B

    // 1) AoS-staged ordered hit collection: 16 bt x 16 seg x 16 roi-groups
    phase1_collect<<<NBT * NSEG * (R_ / RPB), 256, 0, stream>>>(points, rois, counts, hitidx);

    // 2) prefix + gather + zero-fill: one thread per (row, slot)
    phase2_gather<<<(NROW * S_) / 256, 256, 0, stream>>>(points, counts, hitidx, out);
}